// Round 8
// baseline (1145.761 us; speedup 1.0000x reference)
//
#include <hip/hip_runtime.h>
#include <math.h>

// ---------------------------------------------------------------------------
// SheafDiffusion on MI355X — round 7: bucketed two-phase CSR fill.
// Random 4B csr stores (1 dirty line each, ~102 MB traffic) -> bucket-append
// (int2, 782 sequential streams) + per-bucket LDS-cursor distribution
// (contiguous 8KB windows). Also removes k_convert/k_copy.
// ---------------------------------------------------------------------------

#define BSH 7                 // bucket shift: 128 nodes per bucket
#define BSZ (1 << BSH)

__device__ __forceinline__ float gelu_tanh(float x) {
    float x3 = x * x * x;
    float t = tanhf(0.7978845608028654f * (x + 0.044715f * x3));
    return 0.5f * x * (1.0f + t);
}

// ---- edge dtype detection ------------------------------------------------
__global__ void k_detect(const int* __restrict__ ei, int* __restrict__ flag) {
    if (blockIdx.x == 0 && threadIdx.x == 0) {
        int is64 = 1;
        for (int i = 1; i < 256; i += 2)
            if (ei[i] != 0) { is64 = 0; break; }
        *flag = is64;
    }
}

// ---- CSR build -----------------------------------------------------------
// per-node in-degree histogram, reading dst directly from ei
__global__ void k_hist(const int* __restrict__ ei, const int* __restrict__ flag,
                       int* __restrict__ cnt, int e) {
    int i = blockIdx.x * blockDim.x + threadIdx.x;
    if (i >= e) return;
    int d = (*flag) ? ei[2 * (e + i)] : ei[e + i];
    atomicAdd(&cnt[d], 1);
}

__global__ void k_scan1(const int* __restrict__ cnt, int* __restrict__ row_ptr,
                        int* __restrict__ bs, int n) {
    __shared__ int s[256];
    int i = blockIdx.x * 256 + threadIdx.x;
    int v = (i < n) ? cnt[i] : 0;
    s[threadIdx.x] = v;
    __syncthreads();
#pragma unroll
    for (int off = 1; off < 256; off <<= 1) {
        int add = (threadIdx.x >= off) ? s[threadIdx.x - off] : 0;
        __syncthreads();
        s[threadIdx.x] += add;
        __syncthreads();
    }
    if (i < n) row_ptr[i + 1] = s[threadIdx.x];
    if (threadIdx.x == 255) bs[blockIdx.x] = s[255];
}

__global__ void k_scan2(int* __restrict__ bs, int nt) {
    __shared__ int s[1024];
    int t = threadIdx.x;
    s[t] = (t < nt) ? bs[t] : 0;
    __syncthreads();
#pragma unroll
    for (int off = 1; off < 1024; off <<= 1) {
        int add = (t >= off) ? s[t - off] : 0;
        __syncthreads();
        s[t] += add;
        __syncthreads();
    }
    if (t < nt) bs[t] = (t == 0) ? 0 : s[t - 1];
}

__global__ void k_scan3(int* __restrict__ row_ptr, const int* __restrict__ bs, int n) {
    int i = blockIdx.x * 256 + threadIdx.x;
    if (i < n) row_ptr[i + 1] += bs[blockIdx.x];
    if (i == 0) row_ptr[0] = 0;
}

// bucket cursors = row_ptr at bucket starts (buckets are node-aligned)
__global__ void k_binit(const int* __restrict__ row_ptr, int* __restrict__ bcur, int nbk) {
    int b = blockIdx.x * blockDim.x + threadIdx.x;
    if (b < nbk) bcur[b] = row_ptr[b << BSH];
}

// append (src,dst) into dst's bucket region of ebuf
__global__ void k_bucket_fill(const int* __restrict__ ei, const int* __restrict__ flag,
                              int* __restrict__ bcur, int2* __restrict__ ebuf, int e) {
    int i = blockIdx.x * blockDim.x + threadIdx.x;
    if (i >= e) return;
    int s, d;
    if (*flag) { s = ei[2 * i]; d = ei[2 * (e + i)]; }
    else       { s = ei[i];     d = ei[e + i]; }
    int pos = atomicAdd(&bcur[d >> BSH], 1);
    ebuf[pos] = make_int2(s, d);
}

// one block per bucket: distribute bucket edges to per-node csr slots via LDS cursors
__global__ __launch_bounds__(256) void k_fill2(const int* __restrict__ row_ptr,
                       const int2* __restrict__ ebuf, int* __restrict__ csr_src, int n) {
    __shared__ int lcur[BSZ];
    int b = blockIdx.x;
    int node0 = b << BSH;
    int nloc = min(BSZ, n - node0);
    for (int j = threadIdx.x; j < nloc; j += 256) lcur[j] = row_ptr[node0 + j];
    __syncthreads();
    int beg = row_ptr[node0];
    int end = row_ptr[node0 + nloc];
    for (int p = beg + threadIdx.x; p < end; p += 256) {
        int2 ed = ebuf[p];
        int pos = atomicAdd(&lcur[ed.y - node0], 1);
        csr_src[pos] = ed.x;
    }
}

// ---- tiled dense kernels -------------------------------------------------
__global__ __launch_bounds__(256) void k_embed_h(const float* __restrict__ x,
                          const float* __restrict__ W_in, const float* __restrict__ b_in,
                          float* __restrict__ h, int n) {
    __shared__ float sW[128 * 32];
    __shared__ float sX[128 * 68];
    __shared__ float sb[32];
    int tid = threadIdx.x;
    for (int i = tid; i < 128 * 32; i += 256) sW[i] = W_in[i];
    for (int i = tid; i < 32; i += 256) sb[i] = b_in[i];

    int node0 = blockIdx.x * 64;
    int r = tid >> 2;
    int q0 = tid & 3;
    int node_r = node0 + r;
    const float4* xrow = (const float4*)(x + (size_t)node_r * 128);
#pragma unroll
    for (int qq = 0; qq < 8; qq++) {
        int q = qq * 4 + q0;
        float4 v = (node_r < n) ? xrow[q] : make_float4(0.f, 0.f, 0.f, 0.f);
        sX[(q * 4 + 0) * 68 + r] = v.x;
        sX[(q * 4 + 1) * 68 + r] = v.y;
        sX[(q * 4 + 2) * 68 + r] = v.z;
        sX[(q * 4 + 3) * 68 + r] = v.w;
    }
    __syncthreads();

    int tx = tid & 7;
    int ty = tid >> 3;
    float acc[2][4];
#pragma unroll
    for (int i = 0; i < 2; i++)
#pragma unroll
        for (int j = 0; j < 4; j++) acc[i][j] = 0.0f;

#pragma unroll 4
    for (int k = 0; k < 128; k++) {
        float a0 = sX[k * 68 + ty * 2];
        float a1 = sX[k * 68 + ty * 2 + 1];
        float4 wv = *(const float4*)&sW[k * 32 + tx * 4];
#pragma unroll
        for (int j = 0; j < 4; j++) {
            float w = (&wv.x)[j];
            acc[0][j] += a0 * w;
            acc[1][j] += a1 * w;
        }
    }
    float4 bias = make_float4(sb[tx * 4], sb[tx * 4 + 1], sb[tx * 4 + 2], sb[tx * 4 + 3]);
#pragma unroll
    for (int i = 0; i < 2; i++) {
        int node = node0 + ty * 2 + i;
        if (node >= n) continue;
        float4 o;
        o.x = acc[i][0] + bias.x;
        o.y = acc[i][1] + bias.y;
        o.z = acc[i][2] + bias.z;
        o.w = acc[i][3] + bias.w;
        *(float4*)&h[(size_t)node * 32 + tx * 4] = o;
    }
}

__global__ __launch_bounds__(256) void k_embed_m(const float* __restrict__ h,
                          const float* __restrict__ W, const float* __restrict__ b,
                          float* __restrict__ m, int n) {
    __shared__ float sW[32 * 64];
    __shared__ float sA[32 * 68];
    __shared__ float sb[64];
    int tid = threadIdx.x;
    for (int i = tid; i < 32 * 64; i += 256) sW[i] = W[i];
    for (int i = tid; i < 64; i += 256) sb[i] = b[i];

    int node0 = blockIdx.x * 64;
    int r = tid >> 2;
    int q0 = tid & 3;
    int node_r = node0 + r;
    const float4* hrow = (const float4*)(h + (size_t)node_r * 32);
#pragma unroll
    for (int qq = 0; qq < 2; qq++) {
        int q = qq * 4 + q0;
        float4 v = (node_r < n) ? hrow[q] : make_float4(0.f, 0.f, 0.f, 0.f);
        sA[(q * 4 + 0) * 68 + r] = v.x;
        sA[(q * 4 + 1) * 68 + r] = v.y;
        sA[(q * 4 + 2) * 68 + r] = v.z;
        sA[(q * 4 + 3) * 68 + r] = v.w;
    }
    __syncthreads();

    int tx = tid & 15;
    int ty = tid >> 4;
    float acc[4][4];
#pragma unroll
    for (int i = 0; i < 4; i++)
#pragma unroll
        for (int j = 0; j < 4; j++) acc[i][j] = 0.0f;

#pragma unroll 4
    for (int k = 0; k < 32; k++) {
        float4 av = *(const float4*)&sA[k * 68 + ty * 4];
        float4 wv = *(const float4*)&sW[k * 64 + tx * 4];
        float a_[4] = {av.x, av.y, av.z, av.w};
#pragma unroll
        for (int i = 0; i < 4; i++)
#pragma unroll
            for (int j = 0; j < 4; j++)
                acc[i][j] += a_[i] * (&wv.x)[j];
    }
    float4 bias = make_float4(sb[tx * 4], sb[tx * 4 + 1], sb[tx * 4 + 2], sb[tx * 4 + 3]);
#pragma unroll
    for (int i = 0; i < 4; i++) {
        int node = node0 + ty * 4 + i;
        if (node >= n) continue;
        float4 o;
        o.x = gelu_tanh(acc[i][0] + bias.x);
        o.y = gelu_tanh(acc[i][1] + bias.y);
        o.z = gelu_tanh(acc[i][2] + bias.z);
        o.w = gelu_tanh(acc[i][3] + bias.w);
        *(float4*)&m[(size_t)node * 64 + tx * 4] = o;
    }
}

// agg[node] = sum over in-edges of m[src]
__global__ void k_gather64(const int* __restrict__ row_ptr, const int* __restrict__ csr_src,
                           const float* __restrict__ m, float* __restrict__ agg, int n) {
    int wave = (blockIdx.x * blockDim.x + threadIdx.x) >> 6;
    int f = threadIdx.x & 63;
    if (wave >= n) return;
    int beg = row_ptr[wave], end = row_ptr[wave + 1];
    float acc = 0.0f;
    int p = beg;
    for (; p + 1 < end; p += 2) {
        int s0 = csr_src[p], s1 = csr_src[p + 1];
        float a = m[(size_t)s0 * 64 + f];
        float b = m[(size_t)s1 * 64 + f];
        acc += a + b;
    }
    if (p < end) acc += m[(size_t)csr_src[p] * 64 + f];
    agg[(size_t)wave * 64 + f] = acc;
}

// m_out = gelu(m_in @ Ws + agg @ Wn)
__global__ __launch_bounds__(256) void k_gnn(const float* m_in, const float* __restrict__ agg,
                      const float* __restrict__ Ws, const float* __restrict__ Wn,
                      float* m_out, int n) {
    __shared__ float sWs[64 * 64];
    __shared__ float sWn[64 * 64];
    __shared__ float sA[64 * 68];
    int tid = threadIdx.x;
    for (int i = tid; i < 64 * 64; i += 256) { sWs[i] = Ws[i]; sWn[i] = Wn[i]; }
    int node0 = blockIdx.x * 64;
    int tx = tid & 15;
    int ty = tid >> 4;
    float acc[4][4];
#pragma unroll
    for (int i = 0; i < 4; i++)
#pragma unroll
        for (int j = 0; j < 4; j++) acc[i][j] = 0.0f;

#pragma unroll
    for (int phase = 0; phase < 2; phase++) {
        const float* A = phase ? agg : m_in;
        __syncthreads();
        int r0 = tid >> 6;
        int c = tid & 63;
#pragma unroll
        for (int rr = 0; rr < 16; rr++) {
            int r = rr * 4 + r0;
            int node = node0 + r;
            float v = (node < n) ? A[(size_t)node * 64 + c] : 0.0f;
            sA[c * 68 + r] = v;
        }
        __syncthreads();
        const float* w = phase ? sWn : sWs;
#pragma unroll 4
        for (int k = 0; k < 64; k++) {
            float4 av = *(const float4*)&sA[k * 68 + ty * 4];
            float4 wv = *(const float4*)&w[k * 64 + tx * 4];
            float a_[4] = {av.x, av.y, av.z, av.w};
#pragma unroll
            for (int i = 0; i < 4; i++)
#pragma unroll
                for (int j = 0; j < 4; j++)
                    acc[i][j] += a_[i] * (&wv.x)[j];
        }
    }
#pragma unroll
    for (int i = 0; i < 4; i++) {
        int node = node0 + ty * 4 + i;
        if (node >= n) continue;
        float4 o;
        o.x = gelu_tanh(acc[i][0]);
        o.y = gelu_tanh(acc[i][1]);
        o.z = gelu_tanh(acc[i][2]);
        o.w = gelu_tanh(acc[i][3]);
        *(float4*)&m_out[(size_t)node * 64 + tx * 4] = o;
    }
}

__global__ void k_params(const float* __restrict__ m, const float* __restrict__ w2,
                         const float* __restrict__ b2, const int* __restrict__ row_ptr,
                         float4* __restrict__ params, int n) {
    __shared__ float sw[64];
    for (int i = threadIdx.x; i < 64; i += blockDim.x) sw[i] = w2[i];
    __syncthreads();
    int node = blockIdx.x * blockDim.x + threadIdx.x;
    if (node >= n) return;
    float acc = b2[0];
    const float* mr = m + (size_t)node * 64;
#pragma unroll
    for (int k = 0; k < 64; k++) acc += mr[k] * sw[k];
    float theta = tanhf(acc);
    float ang = 6.283185307179586f * theta;
    float c = cosf(ang), s = sinf(ang);
    float deg = (float)(row_ptr[node + 1] - row_ptr[node]);
    float rd = rsqrtf(deg + 1.0f);
    params[node] = make_float4(c, s, rd, 0.0f);
}

__global__ void k_gather_diffuse(const int* __restrict__ row_ptr, const int* __restrict__ csr_src,
                                 const float* __restrict__ xs, const float4* __restrict__ params,
                                 float* __restrict__ aggx, int n) {
    int tid = blockIdx.x * blockDim.x + threadIdx.x;
    int node = tid >> 5;
    int f = tid & 31;
    if (node >= n) return;
    float4 pd = params[node];
    int beg = row_ptr[node], end = row_ptr[node + 1];
    float acc = 0.0f;
    bool lo = (f < 16);
    for (int p = beg; p < end; ++p) {
        int s = csr_src[p];
        float4 ps = params[s];
        float cd = pd.x * ps.x + pd.y * ps.y;
        float sd = ps.y * pd.x - ps.x * pd.y;
        float nrm = ps.z * pd.z;
        float x_own = xs[(size_t)s * 32 + f];
        float x_part = __shfl_xor(x_own, 16, 64);
        float val = lo ? (cd * x_own - sd * x_part) : (sd * x_part + cd * x_own);
        acc += nrm * val;
    }
    aggx[(size_t)node * 32 + f] = acc;
}

__global__ void k_update(float* __restrict__ xs, const float* __restrict__ aggx,
                         const float* __restrict__ Wd, int n) {
    __shared__ float sW[256];
    for (int i = threadIdx.x; i < 256; i += blockDim.x) sW[i] = Wd[i];
    __syncthreads();
    int node = blockIdx.x * blockDim.x + threadIdx.x;
    if (node >= n) return;
    float* xrow = xs + (size_t)node * 32;
    const float* arow = aggx + (size_t)node * 32;
#pragma unroll
    for (int dd = 0; dd < 2; dd++) {
        float xr[16], lx[16];
        const float4* x4 = (const float4*)(xrow + dd * 16);
        const float4* a4 = (const float4*)(arow + dd * 16);
#pragma unroll
        for (int i = 0; i < 4; i++) {
            float4 v = x4[i], a = a4[i];
            xr[4 * i] = v.x; xr[4 * i + 1] = v.y; xr[4 * i + 2] = v.z; xr[4 * i + 3] = v.w;
            lx[4 * i] = v.x - a.x; lx[4 * i + 1] = v.y - a.y;
            lx[4 * i + 2] = v.z - a.z; lx[4 * i + 3] = v.w - a.w;
        }
        float4* xo = (float4*)(xrow + dd * 16);
#pragma unroll
        for (int jq = 0; jq < 4; jq++) {
            float o[4];
#pragma unroll
            for (int jj = 0; jj < 4; jj++) {
                int j = jq * 4 + jj;
                float acc = 0.0f;
#pragma unroll
                for (int k = 0; k < 16; k++) acc += lx[k] * sW[k * 16 + j];
                o[jj] = xr[j] - gelu_tanh(acc);
            }
            xo[jq] = make_float4(o[0], o[1], o[2], o[3]);
        }
    }
}

__global__ void k_out(const float* __restrict__ xs, const float* __restrict__ W,
                      const float* __restrict__ b, float* __restrict__ out, int n) {
    __shared__ float sW[320];
    __shared__ float sb[10];
    for (int i = threadIdx.x; i < 320; i += blockDim.x) sW[i] = W[i];
    for (int i = threadIdx.x; i < 10; i += blockDim.x) sb[i] = b[i];
    __syncthreads();
    int node = blockIdx.x * blockDim.x + threadIdx.x;
    if (node >= n) return;
    float xr[32];
    const float4* x4 = (const float4*)(xs + (size_t)node * 32);
#pragma unroll
    for (int i = 0; i < 8; i++) {
        float4 v = x4[i];
        xr[4 * i] = v.x; xr[4 * i + 1] = v.y; xr[4 * i + 2] = v.z; xr[4 * i + 3] = v.w;
    }
    float* orow = out + (size_t)node * 10;
#pragma unroll
    for (int j = 0; j < 10; j++) {
        float acc = sb[j];
#pragma unroll
        for (int k = 0; k < 32; k++) acc += xr[k] * sW[k * 10 + j];
        orow[j] = acc;
    }
}

static inline size_t align256(size_t x) { return (x + 255) & ~(size_t)255; }

extern "C" void kernel_launch(void* const* d_in, const int* in_sizes, int n_in,
                              void* d_out, int out_size, void* d_ws, size_t ws_size,
                              hipStream_t stream) {
    const float* x      = (const float*)d_in[0];
    const int*   ei     = (const int*)d_in[1];
    const float* W_in   = (const float*)d_in[2];
    const float* b_in   = (const float*)d_in[3];
    const float* emb1_W = (const float*)d_in[4];
    const float* emb1_b = (const float*)d_in[5];
    const float* Ws1    = (const float*)d_in[6];
    const float* Wn1    = (const float*)d_in[7];
    const float* Ws2    = (const float*)d_in[8];
    const float* Wn2    = (const float*)d_in[9];
    const float* emb2_W = (const float*)d_in[10];
    const float* emb2_b = (const float*)d_in[11];
    const float* W_diff = (const float*)d_in[12];
    const float* W_out  = (const float*)d_in[13];
    const float* b_out  = (const float*)d_in[14];

    int n = in_sizes[0] / 128;  // 100000
    int e = in_sizes[1] / 2;    // 1600000
    int nt = (n + 255) / 256;   // node-scan tiles
    int nbk = (n + BSZ - 1) >> BSH;  // buckets

    char* base = (char*)d_ws;
    size_t off = 0;
    int2*  ebuf    = (int2*)(base + off); off = align256(off + (size_t)e * 8);
    int*   csr_src = (int*)(base + off);  off = align256(off + (size_t)e * 4);
    int*   row_ptr = (int*)(base + off);  off = align256(off + (size_t)(n + 1) * 4);
    int*   cnt     = (int*)(base + off);  off = align256(off + (size_t)n * 4);
    int*   bcur    = (int*)(base + off);  off = align256(off + (size_t)nbk * 4);
    int*   bsums   = (int*)(base + off);  off = align256(off + (size_t)nt * 4);
    int*   flag    = (int*)(base + off);  off = align256(off + 16);
    float* h       = (float*)(base + off); off = align256(off + (size_t)n * 32 * 4);
    float* m       = (float*)(base + off); off = align256(off + (size_t)n * 64 * 4);
    float* agg     = (float*)(base + off); off = align256(off + (size_t)n * 64 * 4);
    float4* params = (float4*)(base + off);

    int nb = (n + 255) / 256;
    int eb = (e + 255) / 256;
    int tb64 = (n + 63) / 64;

    // CSR build (bucketed)
    k_detect<<<1, 64, 0, stream>>>(ei, flag);
    hipMemsetAsync(cnt, 0, (size_t)n * 4, stream);
    k_hist<<<eb, 256, 0, stream>>>(ei, flag, cnt, e);
    k_scan1<<<nt, 256, 0, stream>>>(cnt, row_ptr, bsums, n);
    k_scan2<<<1, 1024, 0, stream>>>(bsums, nt);
    k_scan3<<<nt, 256, 0, stream>>>(row_ptr, bsums, n);
    k_binit<<<(nbk + 255) / 256, 256, 0, stream>>>(row_ptr, bcur, nbk);
    k_bucket_fill<<<eb, 256, 0, stream>>>(ei, flag, bcur, ebuf, e);
    k_fill2<<<nbk, 256, 0, stream>>>(row_ptr, ebuf, csr_src, n);

    // embeddings
    k_embed_h<<<tb64, 256, 0, stream>>>(x, W_in, b_in, h, n);
    k_embed_m<<<tb64, 256, 0, stream>>>(h, emb1_W, emb1_b, m, n);

    // sheaf learner GNN layers
    int gb64 = (n * 64 + 255) / 256;
    k_gather64<<<gb64, 256, 0, stream>>>(row_ptr, csr_src, m, agg, n);
    k_gnn<<<tb64, 256, 0, stream>>>(m, agg, Ws1, Wn1, m, n);
    k_gather64<<<gb64, 256, 0, stream>>>(row_ptr, csr_src, m, agg, n);
    k_gnn<<<tb64, 256, 0, stream>>>(m, agg, Ws2, Wn2, m, n);

    k_params<<<nb, 256, 0, stream>>>(m, emb2_W, emb2_b, row_ptr, params, n);

    // diffusion layers
    int gb32 = (n * 32 + 255) / 256;
    for (int l = 0; l < 2; l++) {
        k_gather_diffuse<<<gb32, 256, 0, stream>>>(row_ptr, csr_src, h, params, agg, n);
        k_update<<<nb, 256, 0, stream>>>(h, agg, W_diff + (size_t)l * 256, n);
    }

    k_out<<<nb, 256, 0, stream>>>(h, W_out, b_out, (float*)d_out, n);
}

// Round 9
// 834.041 us; speedup vs baseline: 1.3737x; 1.3737x over previous
//
#include <hip/hip_runtime.h>
#include <math.h>

// ---------------------------------------------------------------------------
// SheafDiffusion on MI355X — round 8: revert bucket fill (atomic contention,
// 378us). Back to per-node-cursor fill, now XCD-sharded by dst range: each
// blockIdx%8 group only writes a contiguous ~0.8MB csr window -> lines stay
// in one XCD's L2, written back once (was 105MB cross-XCD thrash).
// ---------------------------------------------------------------------------

__device__ __forceinline__ float gelu_tanh(float x) {
    float x3 = x * x * x;
    float t = tanhf(0.7978845608028654f * (x + 0.044715f * x3));
    return 0.5f * x * (1.0f + t);
}

// ---- edge dtype detection ------------------------------------------------
__global__ void k_detect(const int* __restrict__ ei, int* __restrict__ flag) {
    if (blockIdx.x == 0 && threadIdx.x == 0) {
        int is64 = 1;
        for (int i = 1; i < 256; i += 2)
            if (ei[i] != 0) { is64 = 0; break; }
        *flag = is64;
    }
}

// ---- CSR build -----------------------------------------------------------
__global__ void k_hist(const int* __restrict__ ei, const int* __restrict__ flag,
                       int* __restrict__ cnt, int e) {
    int i = blockIdx.x * blockDim.x + threadIdx.x;
    if (i >= e) return;
    int d = (*flag) ? ei[2 * (e + i)] : ei[e + i];
    atomicAdd(&cnt[d], 1);
}

__global__ void k_scan1(const int* __restrict__ cnt, int* __restrict__ row_ptr,
                        int* __restrict__ bs, int n) {
    __shared__ int s[256];
    int i = blockIdx.x * 256 + threadIdx.x;
    int v = (i < n) ? cnt[i] : 0;
    s[threadIdx.x] = v;
    __syncthreads();
#pragma unroll
    for (int off = 1; off < 256; off <<= 1) {
        int add = (threadIdx.x >= off) ? s[threadIdx.x - off] : 0;
        __syncthreads();
        s[threadIdx.x] += add;
        __syncthreads();
    }
    if (i < n) row_ptr[i + 1] = s[threadIdx.x];
    if (threadIdx.x == 255) bs[blockIdx.x] = s[255];
}

__global__ void k_scan2(int* __restrict__ bs, int nt) {
    __shared__ int s[1024];
    int t = threadIdx.x;
    s[t] = (t < nt) ? bs[t] : 0;
    __syncthreads();
#pragma unroll
    for (int off = 1; off < 1024; off <<= 1) {
        int add = (t >= off) ? s[t - off] : 0;
        __syncthreads();
        s[t] += add;
        __syncthreads();
    }
    if (t < nt) bs[t] = (t == 0) ? 0 : s[t - 1];
}

__global__ void k_scan3(int* __restrict__ row_ptr, const int* __restrict__ bs, int n) {
    int i = blockIdx.x * 256 + threadIdx.x;
    if (i < n) row_ptr[i + 1] += bs[blockIdx.x];
    if (i == 0) row_ptr[0] = 0;
}

__global__ void k_copy(const int* __restrict__ row_ptr, int* __restrict__ cursor, int n) {
    int i = blockIdx.x * blockDim.x + threadIdx.x;
    if (i < n) cursor[i] = row_ptr[i];
}

// XCD-sharded CSR fill: group g = blockIdx&7 handles dst in [g*ns,(g+1)*ns).
// Each group scans all edges (LLC-absorbed); writes stay in one csr window.
__global__ void k_fill_shard(const int* __restrict__ ei, const int* __restrict__ flag,
                             int* __restrict__ cursor, int* __restrict__ csr_src,
                             int e, int ns) {
    int g = blockIdx.x & 7;
    int lo = g * ns, hi = lo + ns;
    int is64 = *flag;
    int stride = (gridDim.x >> 3) * blockDim.x;
    int i0 = (blockIdx.x >> 3) * blockDim.x + threadIdx.x;
    for (int i = i0; i < e; i += stride) {
        int d = is64 ? ei[2 * (e + i)] : ei[e + i];
        if (d < lo || d >= hi) continue;
        int s = is64 ? ei[2 * i] : ei[i];
        int pos = atomicAdd(&cursor[d], 1);
        csr_src[pos] = s;
    }
}

// ---- tiled dense kernels -------------------------------------------------
__global__ __launch_bounds__(256) void k_embed_h(const float* __restrict__ x,
                          const float* __restrict__ W_in, const float* __restrict__ b_in,
                          float* __restrict__ h, int n) {
    __shared__ float sW[128 * 32];
    __shared__ float sX[128 * 68];
    __shared__ float sb[32];
    int tid = threadIdx.x;
    for (int i = tid; i < 128 * 32; i += 256) sW[i] = W_in[i];
    for (int i = tid; i < 32; i += 256) sb[i] = b_in[i];

    int node0 = blockIdx.x * 64;
    int r = tid >> 2;
    int q0 = tid & 3;
    int node_r = node0 + r;
    const float4* xrow = (const float4*)(x + (size_t)node_r * 128);
#pragma unroll
    for (int qq = 0; qq < 8; qq++) {
        int q = qq * 4 + q0;
        float4 v = (node_r < n) ? xrow[q] : make_float4(0.f, 0.f, 0.f, 0.f);
        sX[(q * 4 + 0) * 68 + r] = v.x;
        sX[(q * 4 + 1) * 68 + r] = v.y;
        sX[(q * 4 + 2) * 68 + r] = v.z;
        sX[(q * 4 + 3) * 68 + r] = v.w;
    }
    __syncthreads();

    int tx = tid & 7;
    int ty = tid >> 3;
    float acc[2][4];
#pragma unroll
    for (int i = 0; i < 2; i++)
#pragma unroll
        for (int j = 0; j < 4; j++) acc[i][j] = 0.0f;

#pragma unroll 4
    for (int k = 0; k < 128; k++) {
        float a0 = sX[k * 68 + ty * 2];
        float a1 = sX[k * 68 + ty * 2 + 1];
        float4 wv = *(const float4*)&sW[k * 32 + tx * 4];
#pragma unroll
        for (int j = 0; j < 4; j++) {
            float w = (&wv.x)[j];
            acc[0][j] += a0 * w;
            acc[1][j] += a1 * w;
        }
    }
    float4 bias = make_float4(sb[tx * 4], sb[tx * 4 + 1], sb[tx * 4 + 2], sb[tx * 4 + 3]);
#pragma unroll
    for (int i = 0; i < 2; i++) {
        int node = node0 + ty * 2 + i;
        if (node >= n) continue;
        float4 o;
        o.x = acc[i][0] + bias.x;
        o.y = acc[i][1] + bias.y;
        o.z = acc[i][2] + bias.z;
        o.w = acc[i][3] + bias.w;
        *(float4*)&h[(size_t)node * 32 + tx * 4] = o;
    }
}

__global__ __launch_bounds__(256) void k_embed_m(const float* __restrict__ h,
                          const float* __restrict__ W, const float* __restrict__ b,
                          float* __restrict__ m, int n) {
    __shared__ float sW[32 * 64];
    __shared__ float sA[32 * 68];
    __shared__ float sb[64];
    int tid = threadIdx.x;
    for (int i = tid; i < 32 * 64; i += 256) sW[i] = W[i];
    for (int i = tid; i < 64; i += 256) sb[i] = b[i];

    int node0 = blockIdx.x * 64;
    int r = tid >> 2;
    int q0 = tid & 3;
    int node_r = node0 + r;
    const float4* hrow = (const float4*)(h + (size_t)node_r * 32);
#pragma unroll
    for (int qq = 0; qq < 2; qq++) {
        int q = qq * 4 + q0;
        float4 v = (node_r < n) ? hrow[q] : make_float4(0.f, 0.f, 0.f, 0.f);
        sA[(q * 4 + 0) * 68 + r] = v.x;
        sA[(q * 4 + 1) * 68 + r] = v.y;
        sA[(q * 4 + 2) * 68 + r] = v.z;
        sA[(q * 4 + 3) * 68 + r] = v.w;
    }
    __syncthreads();

    int tx = tid & 15;
    int ty = tid >> 4;
    float acc[4][4];
#pragma unroll
    for (int i = 0; i < 4; i++)
#pragma unroll
        for (int j = 0; j < 4; j++) acc[i][j] = 0.0f;

#pragma unroll 4
    for (int k = 0; k < 32; k++) {
        float4 av = *(const float4*)&sA[k * 68 + ty * 4];
        float4 wv = *(const float4*)&sW[k * 64 + tx * 4];
        float a_[4] = {av.x, av.y, av.z, av.w};
#pragma unroll
        for (int i = 0; i < 4; i++)
#pragma unroll
            for (int j = 0; j < 4; j++)
                acc[i][j] += a_[i] * (&wv.x)[j];
    }
    float4 bias = make_float4(sb[tx * 4], sb[tx * 4 + 1], sb[tx * 4 + 2], sb[tx * 4 + 3]);
#pragma unroll
    for (int i = 0; i < 4; i++) {
        int node = node0 + ty * 4 + i;
        if (node >= n) continue;
        float4 o;
        o.x = gelu_tanh(acc[i][0] + bias.x);
        o.y = gelu_tanh(acc[i][1] + bias.y);
        o.z = gelu_tanh(acc[i][2] + bias.z);
        o.w = gelu_tanh(acc[i][3] + bias.w);
        *(float4*)&m[(size_t)node * 64 + tx * 4] = o;
    }
}

// agg[node] = sum over in-edges of m[src]
__global__ void k_gather64(const int* __restrict__ row_ptr, const int* __restrict__ csr_src,
                           const float* __restrict__ m, float* __restrict__ agg, int n) {
    int wave = (blockIdx.x * blockDim.x + threadIdx.x) >> 6;
    int f = threadIdx.x & 63;
    if (wave >= n) return;
    int beg = row_ptr[wave], end = row_ptr[wave + 1];
    float acc = 0.0f;
    int p = beg;
    for (; p + 1 < end; p += 2) {
        int s0 = csr_src[p], s1 = csr_src[p + 1];
        float a = m[(size_t)s0 * 64 + f];
        float b = m[(size_t)s1 * 64 + f];
        acc += a + b;
    }
    if (p < end) acc += m[(size_t)csr_src[p] * 64 + f];
    agg[(size_t)wave * 64 + f] = acc;
}

// m_out = gelu(m_in @ Ws + agg @ Wn)
__global__ __launch_bounds__(256) void k_gnn(const float* m_in, const float* __restrict__ agg,
                      const float* __restrict__ Ws, const float* __restrict__ Wn,
                      float* m_out, int n) {
    __shared__ float sWs[64 * 64];
    __shared__ float sWn[64 * 64];
    __shared__ float sA[64 * 68];
    int tid = threadIdx.x;
    for (int i = tid; i < 64 * 64; i += 256) { sWs[i] = Ws[i]; sWn[i] = Wn[i]; }
    int node0 = blockIdx.x * 64;
    int tx = tid & 15;
    int ty = tid >> 4;
    float acc[4][4];
#pragma unroll
    for (int i = 0; i < 4; i++)
#pragma unroll
        for (int j = 0; j < 4; j++) acc[i][j] = 0.0f;

#pragma unroll
    for (int phase = 0; phase < 2; phase++) {
        const float* A = phase ? agg : m_in;
        __syncthreads();
        int r0 = tid >> 6;
        int c = tid & 63;
#pragma unroll
        for (int rr = 0; rr < 16; rr++) {
            int r = rr * 4 + r0;
            int node = node0 + r;
            float v = (node < n) ? A[(size_t)node * 64 + c] : 0.0f;
            sA[c * 68 + r] = v;
        }
        __syncthreads();
        const float* w = phase ? sWn : sWs;
#pragma unroll 4
        for (int k = 0; k < 64; k++) {
            float4 av = *(const float4*)&sA[k * 68 + ty * 4];
            float4 wv = *(const float4*)&w[k * 64 + tx * 4];
            float a_[4] = {av.x, av.y, av.z, av.w};
#pragma unroll
            for (int i = 0; i < 4; i++)
#pragma unroll
                for (int j = 0; j < 4; j++)
                    acc[i][j] += a_[i] * (&wv.x)[j];
        }
    }
#pragma unroll
    for (int i = 0; i < 4; i++) {
        int node = node0 + ty * 4 + i;
        if (node >= n) continue;
        float4 o;
        o.x = gelu_tanh(acc[i][0]);
        o.y = gelu_tanh(acc[i][1]);
        o.z = gelu_tanh(acc[i][2]);
        o.w = gelu_tanh(acc[i][3]);
        *(float4*)&m_out[(size_t)node * 64 + tx * 4] = o;
    }
}

__global__ void k_params(const float* __restrict__ m, const float* __restrict__ w2,
                         const float* __restrict__ b2, const int* __restrict__ row_ptr,
                         float4* __restrict__ params, int n) {
    __shared__ float sw[64];
    for (int i = threadIdx.x; i < 64; i += blockDim.x) sw[i] = w2[i];
    __syncthreads();
    int node = blockIdx.x * blockDim.x + threadIdx.x;
    if (node >= n) return;
    float acc = b2[0];
    const float* mr = m + (size_t)node * 64;
#pragma unroll
    for (int k = 0; k < 64; k++) acc += mr[k] * sw[k];
    float theta = tanhf(acc);
    float ang = 6.283185307179586f * theta;
    float c = cosf(ang), s = sinf(ang);
    float deg = (float)(row_ptr[node + 1] - row_ptr[node]);
    float rd = rsqrtf(deg + 1.0f);
    params[node] = make_float4(c, s, rd, 0.0f);
}

__global__ void k_gather_diffuse(const int* __restrict__ row_ptr, const int* __restrict__ csr_src,
                                 const float* __restrict__ xs, const float4* __restrict__ params,
                                 float* __restrict__ aggx, int n) {
    int tid = blockIdx.x * blockDim.x + threadIdx.x;
    int node = tid >> 5;
    int f = tid & 31;
    if (node >= n) return;
    float4 pd = params[node];
    int beg = row_ptr[node], end = row_ptr[node + 1];
    float acc = 0.0f;
    bool lo = (f < 16);
    for (int p = beg; p < end; ++p) {
        int s = csr_src[p];
        float4 ps = params[s];
        float cd = pd.x * ps.x + pd.y * ps.y;
        float sd = ps.y * pd.x - ps.x * pd.y;
        float nrm = ps.z * pd.z;
        float x_own = xs[(size_t)s * 32 + f];
        float x_part = __shfl_xor(x_own, 16, 64);
        float val = lo ? (cd * x_own - sd * x_part) : (sd * x_part + cd * x_own);
        acc += nrm * val;
    }
    aggx[(size_t)node * 32 + f] = acc;
}

__global__ void k_update(float* __restrict__ xs, const float* __restrict__ aggx,
                         const float* __restrict__ Wd, int n) {
    __shared__ float sW[256];
    for (int i = threadIdx.x; i < 256; i += blockDim.x) sW[i] = Wd[i];
    __syncthreads();
    int node = blockIdx.x * blockDim.x + threadIdx.x;
    if (node >= n) return;
    float* xrow = xs + (size_t)node * 32;
    const float* arow = aggx + (size_t)node * 32;
#pragma unroll
    for (int dd = 0; dd < 2; dd++) {
        float xr[16], lx[16];
        const float4* x4 = (const float4*)(xrow + dd * 16);
        const float4* a4 = (const float4*)(arow + dd * 16);
#pragma unroll
        for (int i = 0; i < 4; i++) {
            float4 v = x4[i], a = a4[i];
            xr[4 * i] = v.x; xr[4 * i + 1] = v.y; xr[4 * i + 2] = v.z; xr[4 * i + 3] = v.w;
            lx[4 * i] = v.x - a.x; lx[4 * i + 1] = v.y - a.y;
            lx[4 * i + 2] = v.z - a.z; lx[4 * i + 3] = v.w - a.w;
        }
        float4* xo = (float4*)(xrow + dd * 16);
#pragma unroll
        for (int jq = 0; jq < 4; jq++) {
            float o[4];
#pragma unroll
            for (int jj = 0; jj < 4; jj++) {
                int j = jq * 4 + jj;
                float acc = 0.0f;
#pragma unroll
                for (int k = 0; k < 16; k++) acc += lx[k] * sW[k * 16 + j];
                o[jj] = xr[j] - gelu_tanh(acc);
            }
            xo[jq] = make_float4(o[0], o[1], o[2], o[3]);
        }
    }
}

__global__ void k_out(const float* __restrict__ xs, const float* __restrict__ W,
                      const float* __restrict__ b, float* __restrict__ out, int n) {
    __shared__ float sW[320];
    __shared__ float sb[10];
    for (int i = threadIdx.x; i < 320; i += blockDim.x) sW[i] = W[i];
    for (int i = threadIdx.x; i < 10; i += blockDim.x) sb[i] = b[i];
    __syncthreads();
    int node = blockIdx.x * blockDim.x + threadIdx.x;
    if (node >= n) return;
    float xr[32];
    const float4* x4 = (const float4*)(xs + (size_t)node * 32);
#pragma unroll
    for (int i = 0; i < 8; i++) {
        float4 v = x4[i];
        xr[4 * i] = v.x; xr[4 * i + 1] = v.y; xr[4 * i + 2] = v.z; xr[4 * i + 3] = v.w;
    }
    float* orow = out + (size_t)node * 10;
#pragma unroll
    for (int j = 0; j < 10; j++) {
        float acc = sb[j];
#pragma unroll
        for (int k = 0; k < 32; k++) acc += xr[k] * sW[k * 10 + j];
        orow[j] = acc;
    }
}

static inline size_t align256(size_t x) { return (x + 255) & ~(size_t)255; }

extern "C" void kernel_launch(void* const* d_in, const int* in_sizes, int n_in,
                              void* d_out, int out_size, void* d_ws, size_t ws_size,
                              hipStream_t stream) {
    const float* x      = (const float*)d_in[0];
    const int*   ei     = (const int*)d_in[1];
    const float* W_in   = (const float*)d_in[2];
    const float* b_in   = (const float*)d_in[3];
    const float* emb1_W = (const float*)d_in[4];
    const float* emb1_b = (const float*)d_in[5];
    const float* Ws1    = (const float*)d_in[6];
    const float* Wn1    = (const float*)d_in[7];
    const float* Ws2    = (const float*)d_in[8];
    const float* Wn2    = (const float*)d_in[9];
    const float* emb2_W = (const float*)d_in[10];
    const float* emb2_b = (const float*)d_in[11];
    const float* W_diff = (const float*)d_in[12];
    const float* W_out  = (const float*)d_in[13];
    const float* b_out  = (const float*)d_in[14];

    int n = in_sizes[0] / 128;  // 100000
    int e = in_sizes[1] / 2;    // 1600000
    int nt = (n + 255) / 256;
    int ns = (n + 7) / 8;       // dst-shard width (8 XCD groups)

    char* base = (char*)d_ws;
    size_t off = 0;
    int*   csr_src = (int*)(base + off);  off = align256(off + (size_t)e * 4);
    int*   row_ptr = (int*)(base + off);  off = align256(off + (size_t)(n + 1) * 4);
    int*   cursor  = (int*)(base + off);  off = align256(off + (size_t)n * 4);
    int*   cnt     = (int*)(base + off);  off = align256(off + (size_t)n * 4);
    int*   bsums   = (int*)(base + off);  off = align256(off + (size_t)nt * 4);
    int*   flag    = (int*)(base + off);  off = align256(off + 16);
    float* h       = (float*)(base + off); off = align256(off + (size_t)n * 32 * 4);
    float* m       = (float*)(base + off); off = align256(off + (size_t)n * 64 * 4);
    float* agg     = (float*)(base + off); off = align256(off + (size_t)n * 64 * 4);
    float4* params = (float4*)(base + off);

    int nb = (n + 255) / 256;
    int eb = (e + 255) / 256;
    int tb64 = (n + 63) / 64;

    // CSR build
    k_detect<<<1, 64, 0, stream>>>(ei, flag);
    hipMemsetAsync(cnt, 0, (size_t)n * 4, stream);
    k_hist<<<eb, 256, 0, stream>>>(ei, flag, cnt, e);
    k_scan1<<<nt, 256, 0, stream>>>(cnt, row_ptr, bsums, n);
    k_scan2<<<1, 1024, 0, stream>>>(bsums, nt);
    k_scan3<<<nt, 256, 0, stream>>>(row_ptr, bsums, n);
    k_copy<<<nb, 256, 0, stream>>>(row_ptr, cursor, n);
    k_fill_shard<<<1024, 256, 0, stream>>>(ei, flag, cursor, csr_src, e, ns);

    // embeddings
    k_embed_h<<<tb64, 256, 0, stream>>>(x, W_in, b_in, h, n);
    k_embed_m<<<tb64, 256, 0, stream>>>(h, emb1_W, emb1_b, m, n);

    // sheaf learner GNN layers
    int gb64 = (n * 64 + 255) / 256;
    k_gather64<<<gb64, 256, 0, stream>>>(row_ptr, csr_src, m, agg, n);
    k_gnn<<<tb64, 256, 0, stream>>>(m, agg, Ws1, Wn1, m, n);
    k_gather64<<<gb64, 256, 0, stream>>>(row_ptr, csr_src, m, agg, n);
    k_gnn<<<tb64, 256, 0, stream>>>(m, agg, Ws2, Wn2, m, n);

    k_params<<<nb, 256, 0, stream>>>(m, emb2_W, emb2_b, row_ptr, params, n);

    // diffusion layers
    int gb32 = (n * 32 + 255) / 256;
    for (int l = 0; l < 2; l++) {
        k_gather_diffuse<<<gb32, 256, 0, stream>>>(row_ptr, csr_src, h, params, agg, n);
        k_update<<<nb, 256, 0, stream>>>(h, agg, W_diff + (size_t)l * 256, n);
    }

    k_out<<<nb, 256, 0, stream>>>(h, W_out, b_out, (float*)d_out, n);
}

// Round 10
// 787.089 us; speedup vs baseline: 1.4557x; 1.0597x over previous
//
#include <hip/hip_runtime.h>
#include <math.h>

// ---------------------------------------------------------------------------
// SheafDiffusion on MI355X — round 9: factor rotations out of the edge loop.
// agg[d] = rd_d R(-th_d) * sum_e ( rd_s R(th_s) xs[s] )  ->  per-node k_rotate
// (O(N)) + pure row-sum gather (k_gather32, 2 edges/wave, x2 unroll) + rotation
// applied in k_update. Also deeper unroll (x4) in k_gather64.
// ---------------------------------------------------------------------------

__device__ __forceinline__ float gelu_tanh(float x) {
    float x3 = x * x * x;
    float t = tanhf(0.7978845608028654f * (x + 0.044715f * x3));
    return 0.5f * x * (1.0f + t);
}

// ---- edge dtype detection ------------------------------------------------
__global__ void k_detect(const int* __restrict__ ei, int* __restrict__ flag) {
    if (blockIdx.x == 0 && threadIdx.x == 0) {
        int is64 = 1;
        for (int i = 1; i < 256; i += 2)
            if (ei[i] != 0) { is64 = 0; break; }
        *flag = is64;
    }
}

// ---- CSR build -----------------------------------------------------------
__global__ void k_hist(const int* __restrict__ ei, const int* __restrict__ flag,
                       int* __restrict__ cnt, int e) {
    int i = blockIdx.x * blockDim.x + threadIdx.x;
    if (i >= e) return;
    int d = (*flag) ? ei[2 * (e + i)] : ei[e + i];
    atomicAdd(&cnt[d], 1);
}

__global__ void k_scan1(const int* __restrict__ cnt, int* __restrict__ row_ptr,
                        int* __restrict__ bs, int n) {
    __shared__ int s[256];
    int i = blockIdx.x * 256 + threadIdx.x;
    int v = (i < n) ? cnt[i] : 0;
    s[threadIdx.x] = v;
    __syncthreads();
#pragma unroll
    for (int off = 1; off < 256; off <<= 1) {
        int add = (threadIdx.x >= off) ? s[threadIdx.x - off] : 0;
        __syncthreads();
        s[threadIdx.x] += add;
        __syncthreads();
    }
    if (i < n) row_ptr[i + 1] = s[threadIdx.x];
    if (threadIdx.x == 255) bs[blockIdx.x] = s[255];
}

__global__ void k_scan2(int* __restrict__ bs, int nt) {
    __shared__ int s[1024];
    int t = threadIdx.x;
    s[t] = (t < nt) ? bs[t] : 0;
    __syncthreads();
#pragma unroll
    for (int off = 1; off < 1024; off <<= 1) {
        int add = (t >= off) ? s[t - off] : 0;
        __syncthreads();
        s[t] += add;
        __syncthreads();
    }
    if (t < nt) bs[t] = (t == 0) ? 0 : s[t - 1];
}

__global__ void k_scan3(int* __restrict__ row_ptr, const int* __restrict__ bs, int n) {
    int i = blockIdx.x * 256 + threadIdx.x;
    if (i < n) row_ptr[i + 1] += bs[blockIdx.x];
    if (i == 0) row_ptr[0] = 0;
}

__global__ void k_copy(const int* __restrict__ row_ptr, int* __restrict__ cursor, int n) {
    int i = blockIdx.x * blockDim.x + threadIdx.x;
    if (i < n) cursor[i] = row_ptr[i];
}

// XCD-sharded CSR fill
__global__ void k_fill_shard(const int* __restrict__ ei, const int* __restrict__ flag,
                             int* __restrict__ cursor, int* __restrict__ csr_src,
                             int e, int ns) {
    int g = blockIdx.x & 7;
    int lo = g * ns, hi = lo + ns;
    int is64 = *flag;
    int stride = (gridDim.x >> 3) * blockDim.x;
    int i0 = (blockIdx.x >> 3) * blockDim.x + threadIdx.x;
    for (int i = i0; i < e; i += stride) {
        int d = is64 ? ei[2 * (e + i)] : ei[e + i];
        if (d < lo || d >= hi) continue;
        int s = is64 ? ei[2 * i] : ei[i];
        int pos = atomicAdd(&cursor[d], 1);
        csr_src[pos] = s;
    }
}

// ---- tiled dense kernels -------------------------------------------------
__global__ __launch_bounds__(256) void k_embed_h(const float* __restrict__ x,
                          const float* __restrict__ W_in, const float* __restrict__ b_in,
                          float* __restrict__ h, int n) {
    __shared__ float sW[128 * 32];
    __shared__ float sX[128 * 68];
    __shared__ float sb[32];
    int tid = threadIdx.x;
    for (int i = tid; i < 128 * 32; i += 256) sW[i] = W_in[i];
    for (int i = tid; i < 32; i += 256) sb[i] = b_in[i];

    int node0 = blockIdx.x * 64;
    int r = tid >> 2;
    int q0 = tid & 3;
    int node_r = node0 + r;
    const float4* xrow = (const float4*)(x + (size_t)node_r * 128);
#pragma unroll
    for (int qq = 0; qq < 8; qq++) {
        int q = qq * 4 + q0;
        float4 v = (node_r < n) ? xrow[q] : make_float4(0.f, 0.f, 0.f, 0.f);
        sX[(q * 4 + 0) * 68 + r] = v.x;
        sX[(q * 4 + 1) * 68 + r] = v.y;
        sX[(q * 4 + 2) * 68 + r] = v.z;
        sX[(q * 4 + 3) * 68 + r] = v.w;
    }
    __syncthreads();

    int tx = tid & 7;
    int ty = tid >> 3;
    float acc[2][4];
#pragma unroll
    for (int i = 0; i < 2; i++)
#pragma unroll
        for (int j = 0; j < 4; j++) acc[i][j] = 0.0f;

#pragma unroll 4
    for (int k = 0; k < 128; k++) {
        float a0 = sX[k * 68 + ty * 2];
        float a1 = sX[k * 68 + ty * 2 + 1];
        float4 wv = *(const float4*)&sW[k * 32 + tx * 4];
#pragma unroll
        for (int j = 0; j < 4; j++) {
            float w = (&wv.x)[j];
            acc[0][j] += a0 * w;
            acc[1][j] += a1 * w;
        }
    }
    float4 bias = make_float4(sb[tx * 4], sb[tx * 4 + 1], sb[tx * 4 + 2], sb[tx * 4 + 3]);
#pragma unroll
    for (int i = 0; i < 2; i++) {
        int node = node0 + ty * 2 + i;
        if (node >= n) continue;
        float4 o;
        o.x = acc[i][0] + bias.x;
        o.y = acc[i][1] + bias.y;
        o.z = acc[i][2] + bias.z;
        o.w = acc[i][3] + bias.w;
        *(float4*)&h[(size_t)node * 32 + tx * 4] = o;
    }
}

__global__ __launch_bounds__(256) void k_embed_m(const float* __restrict__ h,
                          const float* __restrict__ W, const float* __restrict__ b,
                          float* __restrict__ m, int n) {
    __shared__ float sW[32 * 64];
    __shared__ float sA[32 * 68];
    __shared__ float sb[64];
    int tid = threadIdx.x;
    for (int i = tid; i < 32 * 64; i += 256) sW[i] = W[i];
    for (int i = tid; i < 64; i += 256) sb[i] = b[i];

    int node0 = blockIdx.x * 64;
    int r = tid >> 2;
    int q0 = tid & 3;
    int node_r = node0 + r;
    const float4* hrow = (const float4*)(h + (size_t)node_r * 32);
#pragma unroll
    for (int qq = 0; qq < 2; qq++) {
        int q = qq * 4 + q0;
        float4 v = (node_r < n) ? hrow[q] : make_float4(0.f, 0.f, 0.f, 0.f);
        sA[(q * 4 + 0) * 68 + r] = v.x;
        sA[(q * 4 + 1) * 68 + r] = v.y;
        sA[(q * 4 + 2) * 68 + r] = v.z;
        sA[(q * 4 + 3) * 68 + r] = v.w;
    }
    __syncthreads();

    int tx = tid & 15;
    int ty = tid >> 4;
    float acc[4][4];
#pragma unroll
    for (int i = 0; i < 4; i++)
#pragma unroll
        for (int j = 0; j < 4; j++) acc[i][j] = 0.0f;

#pragma unroll 4
    for (int k = 0; k < 32; k++) {
        float4 av = *(const float4*)&sA[k * 68 + ty * 4];
        float4 wv = *(const float4*)&sW[k * 64 + tx * 4];
        float a_[4] = {av.x, av.y, av.z, av.w};
#pragma unroll
        for (int i = 0; i < 4; i++)
#pragma unroll
            for (int j = 0; j < 4; j++)
                acc[i][j] += a_[i] * (&wv.x)[j];
    }
    float4 bias = make_float4(sb[tx * 4], sb[tx * 4 + 1], sb[tx * 4 + 2], sb[tx * 4 + 3]);
#pragma unroll
    for (int i = 0; i < 4; i++) {
        int node = node0 + ty * 4 + i;
        if (node >= n) continue;
        float4 o;
        o.x = gelu_tanh(acc[i][0] + bias.x);
        o.y = gelu_tanh(acc[i][1] + bias.y);
        o.z = gelu_tanh(acc[i][2] + bias.z);
        o.w = gelu_tanh(acc[i][3] + bias.w);
        *(float4*)&m[(size_t)node * 64 + tx * 4] = o;
    }
}

// agg[node] = sum over in-edges of m[src]   (x4 unroll for MLP)
__global__ void k_gather64(const int* __restrict__ row_ptr, const int* __restrict__ csr_src,
                           const float* __restrict__ m, float* __restrict__ agg, int n) {
    int wave = (blockIdx.x * blockDim.x + threadIdx.x) >> 6;
    int f = threadIdx.x & 63;
    if (wave >= n) return;
    int beg = row_ptr[wave], end = row_ptr[wave + 1];
    float acc = 0.0f;
    int p = beg;
    for (; p + 3 < end; p += 4) {
        int s0 = csr_src[p], s1 = csr_src[p + 1], s2 = csr_src[p + 2], s3 = csr_src[p + 3];
        float a = m[(size_t)s0 * 64 + f];
        float b = m[(size_t)s1 * 64 + f];
        float c = m[(size_t)s2 * 64 + f];
        float d = m[(size_t)s3 * 64 + f];
        acc += (a + b) + (c + d);
    }
    for (; p < end; p++) acc += m[(size_t)csr_src[p] * 64 + f];
    agg[(size_t)wave * 64 + f] = acc;
}

// m_out = gelu(m_in @ Ws + agg @ Wn)
__global__ __launch_bounds__(256) void k_gnn(const float* m_in, const float* __restrict__ agg,
                      const float* __restrict__ Ws, const float* __restrict__ Wn,
                      float* m_out, int n) {
    __shared__ float sWs[64 * 64];
    __shared__ float sWn[64 * 64];
    __shared__ float sA[64 * 68];
    int tid = threadIdx.x;
    for (int i = tid; i < 64 * 64; i += 256) { sWs[i] = Ws[i]; sWn[i] = Wn[i]; }
    int node0 = blockIdx.x * 64;
    int tx = tid & 15;
    int ty = tid >> 4;
    float acc[4][4];
#pragma unroll
    for (int i = 0; i < 4; i++)
#pragma unroll
        for (int j = 0; j < 4; j++) acc[i][j] = 0.0f;

#pragma unroll
    for (int phase = 0; phase < 2; phase++) {
        const float* A = phase ? agg : m_in;
        __syncthreads();
        int r0 = tid >> 6;
        int c = tid & 63;
#pragma unroll
        for (int rr = 0; rr < 16; rr++) {
            int r = rr * 4 + r0;
            int node = node0 + r;
            float v = (node < n) ? A[(size_t)node * 64 + c] : 0.0f;
            sA[c * 68 + r] = v;
        }
        __syncthreads();
        const float* w = phase ? sWn : sWs;
#pragma unroll 4
        for (int k = 0; k < 64; k++) {
            float4 av = *(const float4*)&sA[k * 68 + ty * 4];
            float4 wv = *(const float4*)&w[k * 64 + tx * 4];
            float a_[4] = {av.x, av.y, av.z, av.w};
#pragma unroll
            for (int i = 0; i < 4; i++)
#pragma unroll
                for (int j = 0; j < 4; j++)
                    acc[i][j] += a_[i] * (&wv.x)[j];
        }
    }
#pragma unroll
    for (int i = 0; i < 4; i++) {
        int node = node0 + ty * 4 + i;
        if (node >= n) continue;
        float4 o;
        o.x = gelu_tanh(acc[i][0]);
        o.y = gelu_tanh(acc[i][1]);
        o.z = gelu_tanh(acc[i][2]);
        o.w = gelu_tanh(acc[i][3]);
        *(float4*)&m_out[(size_t)node * 64 + tx * 4] = o;
    }
}

// theta -> per-node (cos, sin, rsqrt(deg+1), 0)
__global__ void k_params(const float* __restrict__ m, const float* __restrict__ w2,
                         const float* __restrict__ b2, const int* __restrict__ row_ptr,
                         float4* __restrict__ params, int n) {
    __shared__ float sw[64];
    for (int i = threadIdx.x; i < 64; i += blockDim.x) sw[i] = w2[i];
    __syncthreads();
    int node = blockIdx.x * blockDim.x + threadIdx.x;
    if (node >= n) return;
    float acc = b2[0];
    const float* mr = m + (size_t)node * 64;
#pragma unroll
    for (int k = 0; k < 64; k++) acc += mr[k] * sw[k];
    float theta = tanhf(acc);
    float ang = 6.283185307179586f * theta;
    float c = cosf(ang), s = sinf(ang);
    float deg = (float)(row_ptr[node + 1] - row_ptr[node]);
    float rd = rsqrtf(deg + 1.0f);
    params[node] = make_float4(c, s, rd, 0.0f);
}

// ys = rd * R(theta) * xs   per node (O(N) rotation precompute)
__global__ void k_rotate(const float* __restrict__ xs, const float4* __restrict__ params,
                         float* __restrict__ ys, int n) {
    int tid = blockIdx.x * blockDim.x + threadIdx.x;
    int node = tid >> 4;       // 16 threads per node, one per h-channel
    int hh = tid & 15;
    if (node >= n) return;
    float4 ps = params[node];
    float x0 = xs[(size_t)node * 32 + hh];
    float x1 = xs[(size_t)node * 32 + 16 + hh];
    float y0 = ps.z * (ps.x * x0 - ps.y * x1);
    float y1 = ps.z * (ps.y * x0 + ps.x * x1);
    ys[(size_t)node * 32 + hh] = y0;
    ys[(size_t)node * 32 + 16 + hh] = y1;
}

// S[node] = sum over in-edges of ys[src]  (wave = 2 edges x 32 feats, x2 unroll)
__global__ void k_gather32(const int* __restrict__ row_ptr, const int* __restrict__ csr_src,
                           const float* __restrict__ ys, float* __restrict__ S, int n) {
    int wave = (blockIdx.x * blockDim.x + threadIdx.x) >> 6;
    int lane = threadIdx.x & 63;
    int f = lane & 31;
    int half = lane >> 5;
    if (wave >= n) return;
    int beg = row_ptr[wave], end = row_ptr[wave + 1];
    float acc = 0.0f;
    int p = beg + half;       // this half-wave handles edges p, p+2, p+4, ...
    for (; p + 2 < end; p += 4) {
        int s0 = csr_src[p], s1 = csr_src[p + 2];
        float a = ys[(size_t)s0 * 32 + f];
        float b = ys[(size_t)s1 * 32 + f];
        acc += a + b;
    }
    if (p < end) acc += ys[(size_t)csr_src[p] * 32 + f];
    acc += __shfl_xor(acc, 32, 64);
    if (half == 0) S[(size_t)wave * 32 + f] = acc;
}

// xs = xs - gelu((xs - rd*R(-th)*S) @ Wd)
__global__ void k_update(float* __restrict__ xs, const float* __restrict__ S,
                         const float4* __restrict__ params, const float* __restrict__ Wd,
                         int n) {
    __shared__ float sW[256];
    for (int i = threadIdx.x; i < 256; i += blockDim.x) sW[i] = Wd[i];
    __syncthreads();
    int node = blockIdx.x * blockDim.x + threadIdx.x;
    if (node >= n) return;
    float4 pd = params[node];
    float cd = pd.x, sd = pd.y, rd = pd.z;
    float* xrow = xs + (size_t)node * 32;
    const float* srow = S + (size_t)node * 32;
    float a0[16], a1[16];
#pragma unroll
    for (int i = 0; i < 4; i++) {
        float4 s0 = ((const float4*)srow)[i];
        float4 s1 = ((const float4*)(srow + 16))[i];
        float s0_[4] = {s0.x, s0.y, s0.z, s0.w};
        float s1_[4] = {s1.x, s1.y, s1.z, s1.w};
#pragma unroll
        for (int t = 0; t < 4; t++) {
            a0[4 * i + t] = rd * (cd * s0_[t] + sd * s1_[t]);
            a1[4 * i + t] = rd * (cd * s1_[t] - sd * s0_[t]);
        }
    }
#pragma unroll
    for (int dd = 0; dd < 2; dd++) {
        const float* av = dd ? a1 : a0;
        float xr[16], lx[16];
        const float4* x4 = (const float4*)(xrow + dd * 16);
#pragma unroll
        for (int i = 0; i < 4; i++) {
            float4 v = x4[i];
            xr[4 * i] = v.x; xr[4 * i + 1] = v.y; xr[4 * i + 2] = v.z; xr[4 * i + 3] = v.w;
            lx[4 * i] = v.x - av[4 * i];
            lx[4 * i + 1] = v.y - av[4 * i + 1];
            lx[4 * i + 2] = v.z - av[4 * i + 2];
            lx[4 * i + 3] = v.w - av[4 * i + 3];
        }
        float4* xo = (float4*)(xrow + dd * 16);
#pragma unroll
        for (int jq = 0; jq < 4; jq++) {
            float o[4];
#pragma unroll
            for (int jj = 0; jj < 4; jj++) {
                int j = jq * 4 + jj;
                float acc = 0.0f;
#pragma unroll
                for (int k = 0; k < 16; k++) acc += lx[k] * sW[k * 16 + j];
                o[jj] = xr[j] - gelu_tanh(acc);
            }
            xo[jq] = make_float4(o[0], o[1], o[2], o[3]);
        }
    }
}

__global__ void k_out(const float* __restrict__ xs, const float* __restrict__ W,
                      const float* __restrict__ b, float* __restrict__ out, int n) {
    __shared__ float sW[320];
    __shared__ float sb[10];
    for (int i = threadIdx.x; i < 320; i += blockDim.x) sW[i] = W[i];
    for (int i = threadIdx.x; i < 10; i += blockDim.x) sb[i] = b[i];
    __syncthreads();
    int node = blockIdx.x * blockDim.x + threadIdx.x;
    if (node >= n) return;
    float xr[32];
    const float4* x4 = (const float4*)(xs + (size_t)node * 32);
#pragma unroll
    for (int i = 0; i < 8; i++) {
        float4 v = x4[i];
        xr[4 * i] = v.x; xr[4 * i + 1] = v.y; xr[4 * i + 2] = v.z; xr[4 * i + 3] = v.w;
    }
    float* orow = out + (size_t)node * 10;
#pragma unroll
    for (int j = 0; j < 10; j++) {
        float acc = sb[j];
#pragma unroll
        for (int k = 0; k < 32; k++) acc += xr[k] * sW[k * 10 + j];
        orow[j] = acc;
    }
}

static inline size_t align256(size_t x) { return (x + 255) & ~(size_t)255; }

extern "C" void kernel_launch(void* const* d_in, const int* in_sizes, int n_in,
                              void* d_out, int out_size, void* d_ws, size_t ws_size,
                              hipStream_t stream) {
    const float* x      = (const float*)d_in[0];
    const int*   ei     = (const int*)d_in[1];
    const float* W_in   = (const float*)d_in[2];
    const float* b_in   = (const float*)d_in[3];
    const float* emb1_W = (const float*)d_in[4];
    const float* emb1_b = (const float*)d_in[5];
    const float* Ws1    = (const float*)d_in[6];
    const float* Wn1    = (const float*)d_in[7];
    const float* Ws2    = (const float*)d_in[8];
    const float* Wn2    = (const float*)d_in[9];
    const float* emb2_W = (const float*)d_in[10];
    const float* emb2_b = (const float*)d_in[11];
    const float* W_diff = (const float*)d_in[12];
    const float* W_out  = (const float*)d_in[13];
    const float* b_out  = (const float*)d_in[14];

    int n = in_sizes[0] / 128;  // 100000
    int e = in_sizes[1] / 2;    // 1600000
    int nt = (n + 255) / 256;
    int ns = (n + 7) / 8;

    char* base = (char*)d_ws;
    size_t off = 0;
    int*   csr_src = (int*)(base + off);  off = align256(off + (size_t)e * 4);
    int*   row_ptr = (int*)(base + off);  off = align256(off + (size_t)(n + 1) * 4);
    int*   cursor  = (int*)(base + off);  off = align256(off + (size_t)n * 4);
    int*   cnt     = (int*)(base + off);  off = align256(off + (size_t)n * 4);
    int*   bsums   = (int*)(base + off);  off = align256(off + (size_t)nt * 4);
    int*   flag    = (int*)(base + off);  off = align256(off + 16);
    float* h       = (float*)(base + off); off = align256(off + (size_t)n * 32 * 4);
    float* ys      = (float*)(base + off); off = align256(off + (size_t)n * 32 * 4);
    float* m       = (float*)(base + off); off = align256(off + (size_t)n * 64 * 4);
    float* agg     = (float*)(base + off); off = align256(off + (size_t)n * 64 * 4);
    float4* params = (float4*)(base + off);

    int nb = (n + 255) / 256;
    int eb = (e + 255) / 256;
    int tb64 = (n + 63) / 64;

    // CSR build
    k_detect<<<1, 64, 0, stream>>>(ei, flag);
    hipMemsetAsync(cnt, 0, (size_t)n * 4, stream);
    k_hist<<<eb, 256, 0, stream>>>(ei, flag, cnt, e);
    k_scan1<<<nt, 256, 0, stream>>>(cnt, row_ptr, bsums, n);
    k_scan2<<<1, 1024, 0, stream>>>(bsums, nt);
    k_scan3<<<nt, 256, 0, stream>>>(row_ptr, bsums, n);
    k_copy<<<nb, 256, 0, stream>>>(row_ptr, cursor, n);
    k_fill_shard<<<1024, 256, 0, stream>>>(ei, flag, cursor, csr_src, e, ns);

    // embeddings
    k_embed_h<<<tb64, 256, 0, stream>>>(x, W_in, b_in, h, n);
    k_embed_m<<<tb64, 256, 0, stream>>>(h, emb1_W, emb1_b, m, n);

    // sheaf learner GNN layers
    int gb64 = (n * 64 + 255) / 256;
    k_gather64<<<gb64, 256, 0, stream>>>(row_ptr, csr_src, m, agg, n);
    k_gnn<<<tb64, 256, 0, stream>>>(m, agg, Ws1, Wn1, m, n);
    k_gather64<<<gb64, 256, 0, stream>>>(row_ptr, csr_src, m, agg, n);
    k_gnn<<<tb64, 256, 0, stream>>>(m, agg, Ws2, Wn2, m, n);

    k_params<<<nb, 256, 0, stream>>>(m, emb2_W, emb2_b, row_ptr, params, n);

    // diffusion layers: rotate -> gather -> update (rotation factored out)
    int rb = (n * 16 + 255) / 256;
    for (int l = 0; l < 2; l++) {
        k_rotate<<<rb, 256, 0, stream>>>(h, params, ys, n);
        k_gather32<<<gb64, 256, 0, stream>>>(row_ptr, csr_src, ys, agg, n);
        k_update<<<nb, 256, 0, stream>>>(h, agg, params, W_diff + (size_t)l * 256, n);
    }

    k_out<<<nb, 256, 0, stream>>>(h, W_out, b_out, (float*)d_out, n);
}